// Round 5
// baseline (2130.861 us; speedup 1.0000x reference)
//
#include <hip/hip_runtime.h>

#define TLEN 32768
#define NB 4
#define NLAYER 30

typedef short bf16x8 __attribute__((ext_vector_type(8)));
typedef float f32x16 __attribute__((ext_vector_type(16)));
#define MFMA32(a, b, c) __builtin_amdgcn_mfma_f32_32x32x16_bf16(a, b, c, 0, 0, 0)

__device__ __forceinline__ unsigned short bfh(float x) {
  unsigned int u = __float_as_uint(x);
  return (unsigned short)((u + 0x7fffu + ((u >> 16) & 1u)) >> 16);
}
__device__ __forceinline__ void fsplit(float x, unsigned short& h, unsigned short& l) {
  unsigned int u = __float_as_uint(x);
  unsigned int hb = (u + 0x7fffu + ((u >> 16) & 1u)) & 0xffff0000u;
  h = (unsigned short)(hb >> 16);
  l = bfh(x - __uint_as_float(hb));
}
__device__ __forceinline__ float bflo(unsigned int p) { return __uint_as_float(p << 16); }
__device__ __forceinline__ float bfhi2(unsigned int p) { return __uint_as_float(p & 0xffff0000u); }

__device__ __forceinline__ void split4(float4 v, uint2& h, uint2& l) {
  unsigned short h0, l0, h1, l1, h2, l2, h3, l3;
  fsplit(v.x, h0, l0); fsplit(v.y, h1, l1);
  fsplit(v.z, h2, l2); fsplit(v.w, h3, l3);
  h.x = (unsigned int)h0 | ((unsigned int)h1 << 16);
  h.y = (unsigned int)h2 | ((unsigned int)h3 << 16);
  l.x = (unsigned int)l0 | ((unsigned int)l1 << 16);
  l.y = (unsigned int)l2 | ((unsigned int)l3 << 16);
}
__device__ __forceinline__ bf16x8 asb(uint4 v) {
  union { uint4 u; bf16x8 b; } x; x.u = v; return x.b;
}
__device__ __forceinline__ bf16x8 asb2(uint2 a, uint2 b) {
  union { uint4 u; bf16x8 v; } x;
  x.u.x = a.x; x.u.y = a.y; x.u.z = b.x; x.u.w = b.y; return x.v;
}
__device__ __forceinline__ float fast_sigmoid(float x) { return 1.0f / (1.0f + __expf(-x)); }
__device__ __forceinline__ float fast_tanh(float x) { return 1.0f - 2.0f / (1.0f + __expf(2.0f * x)); }

// Fragment-ordered weight layout: uint4 index (((s>>5)*nkc + kc)*2 + q)*32 + (s&31)
// holds shorts (s, k=kc*16+q*8 .. +8).
__device__ __forceinline__ unsigned int fragOff(int s, int k, int nkc) {
  return ((((unsigned)(s >> 5) * nkc + (k >> 4)) * 2 + ((k >> 3) & 1)) * 32 + (s & 31)) * 8 + (k & 7);
}

// ---------------- prep ----------------

// chunk-local causal conv: x[b][ti][hi 0..63 | lo 64..127]
__global__ __launch_bounds__(256) void wn_causal_k(
    const float* __restrict__ y, const float* __restrict__ cw,
    const float* __restrict__ cb, unsigned short* __restrict__ xt, int base, int cext) {
  int ti = blockIdx.x * 64 + (threadIdx.x >> 2);
  int cg = (threadIdx.x & 3) << 4;
  int b = blockIdx.y;
  float yv = y[(size_t)b * TLEN + base + ti];
  unsigned short* o = xt + ((size_t)b * cext + ti) * 128 + cg;
  uint2 h[4], l[4];
#pragma unroll
  for (int j = 0; j < 4; ++j) {
    float4 w = *(const float4*)(cw + cg + 4 * j);
    float4 bb = *(const float4*)(cb + cg + 4 * j);
    float4 v; v.x = w.x * yv + bb.x; v.y = w.y * yv + bb.y;
    v.z = w.z * yv + bb.z; v.w = w.w * yv + bb.w;
    split4(v, h[j], l[j]);
  }
  uint4 H0, H1, L0, L1;
  H0.x = h[0].x; H0.y = h[0].y; H0.z = h[1].x; H0.w = h[1].y;
  H1.x = h[2].x; H1.y = h[2].y; H1.z = h[3].x; H1.w = h[3].y;
  L0.x = l[0].x; L0.y = l[0].y; L0.z = l[1].x; L0.w = l[1].y;
  L1.x = l[2].x; L1.y = l[2].y; L1.z = l[3].x; L1.w = l[3].y;
  *(uint4*)(o) = H0; *(uint4*)(o + 8) = H1;
  *(uint4*)(o + 64) = L0; *(uint4*)(o + 72) = L1;
}

// filt/gate -> fragment-ordered hi/lo (k = tap*64 + r)
__global__ __launch_bounds__(256) void wn_prep_fg_k(
    const float* __restrict__ filt, const float* __restrict__ gate,
    unsigned short* __restrict__ fH, unsigned short* __restrict__ fL,
    unsigned short* __restrict__ gH, unsigned short* __restrict__ gL) {
  int id = blockIdx.x * 256 + threadIdx.x;  // NLAYER*64*128
  int i = id >> 13; int rem = id & 8191; int d = rem >> 7; int k = rem & 127;
  int tap = k >> 6, r = k & 63;
  size_t sb = (size_t)i * 8192;
  unsigned int off = fragOff(d, k, 8);
  unsigned short h, l;
  fsplit(filt[sb + d * 128 + r * 2 + tap], h, l); fH[sb + off] = h; fL[sb + off] = l;
  fsplit(gate[sb + d * 128 + r * 2 + tap], h, l); gH[sb + off] = h; gL[sb + off] = l;
}

// generic row-major [layers][M][K] fp32 -> fragment-ordered hi/lo
__global__ __launch_bounds__(256) void wn_repackA_k(
    const float* __restrict__ src, unsigned short* __restrict__ dH,
    unsigned short* __restrict__ dL, int kShift, int mkShift) {
  int id = blockIdx.x * 256 + threadIdx.x;
  int layer = id >> mkShift;
  int rem = id & ((1 << mkShift) - 1);
  int s = rem >> kShift;
  int k = rem & ((1 << kShift) - 1);
  int nkc = 1 << (kShift - 4);
  unsigned int off = fragOff(s, k, nkc);
  size_t base = (size_t)layer << mkShift;
  unsigned short h, l;
  fsplit(src[base + rem], h, l);
  dH[base + off] = h; dL[base + off] = l;
}

// ---------------- layer kernel (chunk-local) ----------------
// outs is written in B-FRAGMENT order: per (b,tile): [fg=kc*2+q 0..8)[t 0..64)[8 shorts]
__global__ __launch_bounds__(256, 3) void wn_layer_k(
    const unsigned short* __restrict__ xin, unsigned short* __restrict__ xout,
    unsigned short* __restrict__ outp,  // [NB][ntiles][8][64][8] bf16
    const unsigned short* __restrict__ fH, const unsigned short* __restrict__ fL,
    const unsigned short* __restrict__ gH, const unsigned short* __restrict__ gL,
    const unsigned short* __restrict__ rH, const unsigned short* __restrict__ rL,
    int dil, int ti_start, int lo, int cext, int tc) {
  __shared__ unsigned short Xs[64 * 260];
  __shared__ unsigned short Os[64 * 132];  // [t][d hi 0..64 | d lo 64..128]

  const int tid = threadIdx.x;
  const int lane = tid & 63, wave = tid >> 6;
  const int q = lane >> 5, ln = lane & 31;
  const int b = blockIdx.y;
  const int ti0 = ti_start + (int)blockIdx.x * 64;
  const unsigned short* xb = xin + (size_t)b * cext * 128;

  // ---- stage X tile (coalesced copy) ----
  {
    int row = tid >> 2, cg = (tid & 3) << 4;
    const unsigned short* src = xb + (size_t)(ti0 + row) * 128 + cg;
    unsigned short* dh = &Xs[row * 260 + 64 + cg];
    unsigned short* dl = &Xs[row * 260 + 192 + cg];
    {
      uint4 h0 = *(const uint4*)(src);
      uint4 h1 = *(const uint4*)(src + 8);
      uint4 l0 = *(const uint4*)(src + 64);
      uint4 l1 = *(const uint4*)(src + 72);
      uint2 t;
      t.x = h0.x; t.y = h0.y; *(uint2*)(dh + 0) = t;
      t.x = h0.z; t.y = h0.w; *(uint2*)(dh + 4) = t;
      t.x = h1.x; t.y = h1.y; *(uint2*)(dh + 8) = t;
      t.x = h1.z; t.y = h1.w; *(uint2*)(dh + 12) = t;
      t.x = l0.x; t.y = l0.y; *(uint2*)(dl + 0) = t;
      t.x = l0.z; t.y = l0.w; *(uint2*)(dl + 4) = t;
      t.x = l1.x; t.y = l1.y; *(uint2*)(dl + 8) = t;
      t.x = l1.z; t.y = l1.w; *(uint2*)(dl + 12) = t;
    }
    int ts = ti0 + row - dil;
    dh = &Xs[row * 260 + cg];
    dl = &Xs[row * 260 + 128 + cg];
    if (ts >= 0) {
      const unsigned short* s2 = xb + (size_t)ts * 128 + cg;
      uint4 h0 = *(const uint4*)(s2);
      uint4 h1 = *(const uint4*)(s2 + 8);
      uint4 l0 = *(const uint4*)(s2 + 64);
      uint4 l1 = *(const uint4*)(s2 + 72);
      uint2 t;
      t.x = h0.x; t.y = h0.y; *(uint2*)(dh + 0) = t;
      t.x = h0.z; t.y = h0.w; *(uint2*)(dh + 4) = t;
      t.x = h1.x; t.y = h1.y; *(uint2*)(dh + 8) = t;
      t.x = h1.z; t.y = h1.w; *(uint2*)(dh + 12) = t;
      t.x = l0.x; t.y = l0.y; *(uint2*)(dl + 0) = t;
      t.x = l0.z; t.y = l0.w; *(uint2*)(dl + 4) = t;
      t.x = l1.x; t.y = l1.y; *(uint2*)(dl + 8) = t;
      t.x = l1.z; t.y = l1.w; *(uint2*)(dl + 12) = t;
    } else {
      uint2 z; z.x = 0; z.y = 0;
#pragma unroll
      for (int j = 0; j < 4; ++j) { *(uint2*)(dh + 4 * j) = z; *(uint2*)(dl + 4 * j) = z; }
    }
  }

  const int dblk = wave >> 1, tblk = wave & 1;

  // conv A-frags (fragment-ordered, coalesced): hi register-resident, lo streamed
  uint4 afh[8], agh[8];
  const uint4* pfh = (const uint4*)fH;
  const uint4* pfl = (const uint4*)fL;
  const uint4* pgh = (const uint4*)gH;
  const uint4* pgl = (const uint4*)gL;
  const int abase = dblk * 512 + q * 32 + ln;
#pragma unroll
  for (int kc = 0; kc < 8; ++kc) {
    afh[kc] = pfh[abase + kc * 64];
    agh[kc] = pgh[abase + kc * 64];
  }
  __syncthreads();

  f32x16 accF, accG;
#pragma unroll
  for (int i = 0; i < 16; ++i) { accF[i] = 0.f; accG[i] = 0.f; }

  const unsigned short* xrow = &Xs[(tblk * 32 + ln) * 260];
#pragma unroll
  for (int kc = 0; kc < 8; ++kc) {
    uint4 fl = pfl[abase + kc * 64];
    uint4 gl = pgl[abase + kc * 64];
    uint2 h0 = *(const uint2*)(xrow + kc * 16 + q * 8);
    uint2 h1 = *(const uint2*)(xrow + kc * 16 + q * 8 + 4);
    uint2 l0 = *(const uint2*)(xrow + 128 + kc * 16 + q * 8);
    uint2 l1 = *(const uint2*)(xrow + 128 + kc * 16 + q * 8 + 4);
    bf16x8 bh = asb2(h0, h1), bl = asb2(l0, l1);
    accF = MFMA32(asb(afh[kc]), bh, accF);
    accF = MFMA32(asb(afh[kc]), bl, accF);
    accF = MFMA32(asb(fl), bh, accF);
    accG = MFMA32(asb(agh[kc]), bh, accG);
    accG = MFMA32(asb(agh[kc]), bl, accG);
    accG = MFMA32(asb(gl), bh, accG);
  }

  // ---- activation -> Os (hi/lo) ----
  {
    int trow = tblk * 32 + ln;
    unsigned short* orow = &Os[trow * 132 + dblk * 32];
#pragma unroll
    for (int g = 0; g < 4; ++g) {
      int dofs = 8 * g + 4 * q;
      unsigned short oh[4], ol[4];
#pragma unroll
      for (int j = 0; j < 4; ++j) {
        float f = fast_tanh(accF[g * 4 + j]) * fast_sigmoid(accG[g * 4 + j]);
        fsplit(f, oh[j], ol[j]);
      }
      uint2 hv, lv;
      hv.x = (unsigned int)oh[0] | ((unsigned int)oh[1] << 16);
      hv.y = (unsigned int)oh[2] | ((unsigned int)oh[3] << 16);
      lv.x = (unsigned int)ol[0] | ((unsigned int)ol[1] << 16);
      lv.y = (unsigned int)ol[2] | ((unsigned int)ol[3] << 16);
      *(uint2*)(orow + dofs) = hv;
      *(uint2*)(orow + 64 + dofs) = lv;
    }
  }
  __syncthreads();

  // ---- outs store in B-fragment order (hi halves from Os), coalesced ----
  if (ti0 >= lo) {
    int tile = (ti0 - lo) >> 6;
    int t = tid & 63, fg = tid >> 6;  // fg 0..3 here, fg+4 below
    const unsigned short* sp = &Os[t * 132];
    uint2 a0 = *(const uint2*)(sp + fg * 8);
    uint2 a1 = *(const uint2*)(sp + fg * 8 + 4);
    uint2 c0 = *(const uint2*)(sp + 32 + fg * 8);
    uint2 c1 = *(const uint2*)(sp + 32 + fg * 8 + 4);
    uint4 v0, v1;
    v0.x = a0.x; v0.y = a0.y; v0.z = a1.x; v0.w = a1.y;
    v1.x = c0.x; v1.y = c0.y; v1.z = c1.x; v1.w = c1.y;
    unsigned short* dpb = outp + ((size_t)b * (tc >> 6) + tile) * 4096;
    *(uint4*)(dpb + fg * 512 + t * 8) = v0;
    *(uint4*)(dpb + (fg + 4) * 512 + t * 8) = v1;
  }

  // ---- residual: xout = x + res_w @ out (store via LDS repack) ----
  {
    const int rblk = wave >> 1, tb2 = wave & 1;
    const int rb4 = rblk * 256 + q * 32 + ln;
    const uint4* prh = (const uint4*)rH;
    const uint4* prl = (const uint4*)rL;
    uint4 arh[4], arl[4];
#pragma unroll
    for (int kc = 0; kc < 4; ++kc) {
      arh[kc] = prh[rb4 + kc * 64];
      arl[kc] = prl[rb4 + kc * 64];
    }
    f32x16 accR;
#pragma unroll
    for (int i = 0; i < 16; ++i) accR[i] = 0.f;
    const int t = tb2 * 32 + ln;
    const unsigned short* orow = &Os[t * 132];
#pragma unroll
    for (int kc = 0; kc < 4; ++kc) {
      uint2 h0 = *(const uint2*)(orow + kc * 16 + q * 8);
      uint2 h1 = *(const uint2*)(orow + kc * 16 + q * 8 + 4);
      uint2 l0 = *(const uint2*)(orow + 64 + kc * 16 + q * 8);
      uint2 l1 = *(const uint2*)(orow + 64 + kc * 16 + q * 8 + 4);
      bf16x8 bh = asb2(h0, h1), bl = asb2(l0, l1);
      accR = MFMA32(asb(arh[kc]), bh, accR);
      accR = MFMA32(asb(arh[kc]), bl, accR);
      accR = MFMA32(asb(arl[kc]), bh, accR);
    }
    __syncthreads();  // all Os reads (outs copy + accR MFMAs) complete
    // v = accR + x -> split -> Os as [t][hi 0..64 | lo 64..128]
#pragma unroll
    for (int g = 0; g < 4; ++g) {
      int rbase = rblk * 32 + 8 * g + 4 * q;
      uint2 xh = *(const uint2*)&Xs[t * 260 + 64 + rbase];
      uint2 xl = *(const uint2*)&Xs[t * 260 + 192 + rbase];
      float4 v;
      v.x = accR[g * 4 + 0] + bflo(xh.x) + bflo(xl.x);
      v.y = accR[g * 4 + 1] + bfhi2(xh.x) + bfhi2(xl.x);
      v.z = accR[g * 4 + 2] + bflo(xh.y) + bflo(xl.y);
      v.w = accR[g * 4 + 3] + bfhi2(xh.y) + bfhi2(xl.y);
      uint2 hv, lv;
      split4(v, hv, lv);
      *(uint2*)&Os[t * 132 + rbase] = hv;
      *(uint2*)&Os[t * 132 + 64 + rbase] = lv;
    }
    __syncthreads();
    // coalesced xout copy: 4 threads/row, 64B each
    int row = tid >> 2, seg = (tid & 3) << 5;
    const unsigned short* sp = &Os[row * 132 + seg];
    uint2 a0 = *(const uint2*)(sp);
    uint2 a1 = *(const uint2*)(sp + 4);
    uint2 a2 = *(const uint2*)(sp + 8);
    uint2 a3 = *(const uint2*)(sp + 12);
    uint2 a4 = *(const uint2*)(sp + 16);
    uint2 a5 = *(const uint2*)(sp + 20);
    uint2 a6 = *(const uint2*)(sp + 24);
    uint2 a7 = *(const uint2*)(sp + 28);
    uint4 w0, w1, w2, w3;
    w0.x = a0.x; w0.y = a0.y; w0.z = a1.x; w0.w = a1.y;
    w1.x = a2.x; w1.y = a2.y; w1.z = a3.x; w1.w = a3.y;
    w2.x = a4.x; w2.y = a4.y; w2.z = a5.x; w2.w = a5.y;
    w3.x = a6.x; w3.y = a6.y; w3.z = a7.x; w3.w = a7.y;
    unsigned short* dp = xout + ((size_t)b * cext + ti0 + row) * 128 + seg;
    *(uint4*)(dp) = w0; *(uint4*)(dp + 8) = w1;
    *(uint4*)(dp + 16) = w2; *(uint4*)(dp + 24) = w3;
  }
}

// ---------------- fused skip-sum + head (per chunk) ----------------
// Skip loop: barrier-free, LDS-free, SOFTWARE-PIPELINED. Two named register
// sets ping-pong at layer granularity: layer i+1's B (HBM) and A-hi (L2) loads
// are issued before layer i's MFMAs; A-lo preloads at compute start.
__global__ __launch_bounds__(256, 2) void wn_skipend_k(
    const unsigned short* __restrict__ outs,  // [30][NB][ntiles][8][64][8]
    const unsigned short* __restrict__ sH, const unsigned short* __restrict__ sL,
    const unsigned short* __restrict__ e1H, const unsigned short* __restrict__ e1L,
    const float* __restrict__ b1,
    const unsigned short* __restrict__ e2H, const unsigned short* __restrict__ e2L,
    const float* __restrict__ b2, float* __restrict__ out, int c0, int tc) {
  __shared__ unsigned short SM[64 * 260];  // Hs for head phases; fp32 out repack

  const int tid = threadIdx.x;
  const int lane = tid & 63, wave = tid >> 6;
  const int q = lane >> 5, ln = lane & 31;
  const int b = blockIdx.y;
  const int tl0 = (int)blockIdx.x * 64;

  f32x16 acc[4];  // [sblk][tt]
#pragma unroll
  for (int a = 0; a < 4; ++a)
#pragma unroll
    for (int i = 0; i < 16; ++i) acc[a][i] = 0.f;

  const int ntiles = tc >> 6;
  const size_t lstride4 = (size_t)NB * tc * 8;  // uint4 per layer
  const uint4* pbl = (const uint4*)outs + ((size_t)b * ntiles + blockIdx.x) * 512
                   + q * 64 + ln;               // lane-resolved fragment base
  const int ab = wave * 512 + q * 32 + ln;      // fragment-ordered A base (uint4)
  const uint4* pa4 = (const uint4*)sH;
  const uint4* pl4 = (const uint4*)sL;

  uint4 bbA[8], ahA[8], bbB[8], ahB[8];

#define LDSET(i, bb, ah)                                          \
  {                                                               \
    const uint4* pb_ = pbl + (size_t)(i) * lstride4;              \
    const uint4* pa_ = pa4 + (size_t)(i) * 2048;                  \
    _Pragma("unroll")                                             \
    for (int kc = 0; kc < 4; ++kc) {                              \
      bb[kc * 2] = pb_[kc * 128];                                 \
      bb[kc * 2 + 1] = pb_[kc * 128 + 32];                        \
      ah[kc * 2] = pa_[ab + kc * 64];                             \
      ah[kc * 2 + 1] = pa_[ab + 256 + kc * 64];                   \
    }                                                             \
  }

#define CPSET(i, bb, ah)                                                      \
  {                                                                           \
    const uint4* pl_ = pl4 + (size_t)(i) * 2048;                              \
    uint4 al[8];                                                              \
    _Pragma("unroll")                                                         \
    for (int kc = 0; kc < 4; ++kc) {                                          \
      al[kc * 2] = pl_[ab + kc * 64];                                         \
      al[kc * 2 + 1] = pl_[ab + 256 + kc * 64];                               \
    }                                                                         \
    _Pragma("unroll")                                                         \
    for (int kc = 0; kc < 4; ++kc) {                                          \
      _Pragma("unroll")                                                       \
      for (int sblk = 0; sblk < 2; ++sblk) {                                  \
        acc[sblk * 2 + 0] = MFMA32(asb(ah[kc * 2 + sblk]), asb(bb[kc * 2]),   \
                                   acc[sblk * 2 + 0]);                        \
        acc[sblk * 2 + 0] = MFMA32(asb(al[kc * 2 + sblk]), asb(bb[kc * 2]),   \
                                   acc[sblk * 2 + 0]);                        \
        acc[sblk * 2 + 1] = MFMA32(asb(ah[kc * 2 + sblk]), asb(bb[kc * 2 + 1]),\
                                   acc[sblk * 2 + 1]);                        \
        acc[sblk * 2 + 1] = MFMA32(asb(al[kc * 2 + sblk]), asb(bb[kc * 2 + 1]),\
                                   acc[sblk * 2 + 1]);                        \
      }                                                                       \
    }                                                                         \
  }

  LDSET(0, bbA, ahA);
  for (int i = 0; i < NLAYER; i += 2) {
    LDSET(i + 1, bbB, ahB);
    CPSET(i, bbA, ahA);
    if (i + 2 < NLAYER) LDSET(i + 2, bbA, ahA);
    CPSET(i + 1, bbB, ahB);
  }
#undef LDSET
#undef CPSET

  // h = relu(skip) -> Hs bf16 (row stride 260); first LDS touch
#pragma unroll
  for (int sblk = 0; sblk < 2; ++sblk)
#pragma unroll
    for (int tt = 0; tt < 2; ++tt) {
      int t = tt * 32 + ln;
#pragma unroll
      for (int g = 0; g < 4; ++g) {
        int s = wave * 64 + sblk * 32 + 8 * g + 4 * q;
        unsigned short h0 = bfh(fmaxf(acc[sblk * 2 + tt][g * 4 + 0], 0.f));
        unsigned short h1 = bfh(fmaxf(acc[sblk * 2 + tt][g * 4 + 1], 0.f));
        unsigned short h2 = bfh(fmaxf(acc[sblk * 2 + tt][g * 4 + 2], 0.f));
        unsigned short h3 = bfh(fmaxf(acc[sblk * 2 + tt][g * 4 + 3], 0.f));
        uint2 hv;
        hv.x = (unsigned int)h0 | ((unsigned int)h1 << 16);
        hv.y = (unsigned int)h2 | ((unsigned int)h3 << 16);
        *(uint2*)&SM[t * 260 + s] = hv;
      }
    }
  __syncthreads();

  // e1: acc = e1 @ h
#pragma unroll
  for (int a = 0; a < 4; ++a)
#pragma unroll
    for (int i = 0; i < 16; ++i) acc[a][i] = 0.f;
  const uint4* p1h = (const uint4*)e1H;
  const uint4* p1l = (const uint4*)e1L;
  const int eb = wave * 2048 + q * 32 + ln;
#pragma unroll 4
  for (int kc = 0; kc < 16; ++kc) {
#pragma unroll
    for (int ot = 0; ot < 2; ++ot) {
      uint4 ah = p1h[eb + ot * 1024 + kc * 64];
      uint4 al = p1l[eb + ot * 1024 + kc * 64];
#pragma unroll
      for (int tt = 0; tt < 2; ++tt) {
        uint2 b0 = *(const uint2*)&SM[(tt * 32 + ln) * 260 + kc * 16 + q * 8];
        uint2 b1v = *(const uint2*)&SM[(tt * 32 + ln) * 260 + kc * 16 + q * 8 + 4];
        bf16x8 bb = asb2(b0, b1v);
        acc[ot * 2 + tt] = MFMA32(asb(ah), bb, acc[ot * 2 + tt]);
        acc[ot * 2 + tt] = MFMA32(asb(al), bb, acc[ot * 2 + tt]);
      }
    }
  }
  __syncthreads();
  // h2 = relu(acc + b1) -> Hs
#pragma unroll
  for (int ot = 0; ot < 2; ++ot)
#pragma unroll
    for (int tt = 0; tt < 2; ++tt) {
      int t = tt * 32 + ln;
#pragma unroll
      for (int g = 0; g < 4; ++g) {
        int o = wave * 64 + ot * 32 + 8 * g + 4 * q;
        float4 bb = *(const float4*)(b1 + o);
        unsigned short h0 = bfh(fmaxf(acc[ot * 2 + tt][g * 4 + 0] + bb.x, 0.f));
        unsigned short h1 = bfh(fmaxf(acc[ot * 2 + tt][g * 4 + 1] + bb.y, 0.f));
        unsigned short h2 = bfh(fmaxf(acc[ot * 2 + tt][g * 4 + 2] + bb.z, 0.f));
        unsigned short h3 = bfh(fmaxf(acc[ot * 2 + tt][g * 4 + 3] + bb.w, 0.f));
        uint2 hv;
        hv.x = (unsigned int)h0 | ((unsigned int)h1 << 16);
        hv.y = (unsigned int)h2 | ((unsigned int)h3 << 16);
        *(uint2*)&SM[t * 260 + o] = hv;
      }
    }
  __syncthreads();

  // e2: acc = e2 @ h2
#pragma unroll
  for (int a = 0; a < 4; ++a)
#pragma unroll
    for (int i = 0; i < 16; ++i) acc[a][i] = 0.f;
  const uint4* p2h = (const uint4*)e2H;
  const uint4* p2l = (const uint4*)e2L;
#pragma unroll 4
  for (int kc = 0; kc < 16; ++kc) {
#pragma unroll
    for (int ot = 0; ot < 2; ++ot) {
      uint4 ah = p2h[eb + ot * 1024 + kc * 64];
      uint4 al = p2l[eb + ot * 1024 + kc * 64];
#pragma unroll
      for (int tt = 0; tt < 2; ++tt) {
        uint2 b0 = *(const uint2*)&SM[(tt * 32 + ln) * 260 + kc * 16 + q * 8];
        uint2 b1v = *(const uint2*)&SM[(tt * 32 + ln) * 260 + kc * 16 + q * 8 + 4];
        bf16x8 bb = asb2(b0, b1v);
        acc[ot * 2 + tt] = MFMA32(asb(ah), bb, acc[ot * 2 + tt]);
        acc[ot * 2 + tt] = MFMA32(asb(al), bb, acc[ot * 2 + tt]);
      }
    }
  }
  __syncthreads();  // h2 reads done; SM reusable as fp32 repack buffer

  // final store via LDS repack (two 32-row half-passes), full-sector coalesced
  float* SMf = (float*)SM;  // [32][260] fp32
#pragma unroll
  for (int hp = 0; hp < 2; ++hp) {
#pragma unroll
    for (int ot = 0; ot < 2; ++ot)
#pragma unroll
      for (int g = 0; g < 4; ++g) {
        int o = wave * 64 + ot * 32 + 8 * g + 4 * q;
        float4 bb = *(const float4*)(b2 + o);
        float2 v0, v1;
        v0.x = acc[ot * 2 + hp][g * 4 + 0] + bb.x;
        v0.y = acc[ot * 2 + hp][g * 4 + 1] + bb.y;
        v1.x = acc[ot * 2 + hp][g * 4 + 2] + bb.z;
        v1.y = acc[ot * 2 + hp][g * 4 + 3] + bb.w;
        *(float2*)&SMf[ln * 260 + o] = v0;
        *(float2*)&SMf[ln * 260 + o + 2] = v1;
      }
    __syncthreads();
    {
      // 8 threads/row, each 16B at 16B-consecutive addresses -> full 128B rows
      int row = tid >> 3, c4 = (tid & 7) << 2;
      float* op = out + ((size_t)b * TLEN + c0 + tl0 + hp * 32 + row) * 256 + c4;
      const float* spf = &SMf[row * 260 + c4];
#pragma unroll
      for (int j = 0; j < 8; ++j) *(float4*)(op + 32 * j) = *(const float4*)(spf + 32 * j);
    }
    if (hp == 0) __syncthreads();
  }
}

extern "C" void kernel_launch(void* const* d_in, const int* in_sizes, int n_in,
                              void* d_out, int out_size, void* d_ws,
                              size_t ws_size, hipStream_t stream) {
  (void)in_sizes; (void)n_in; (void)out_size;
  const float* y     = (const float*)d_in[0];
  const float* cw    = (const float*)d_in[1];
  const float* cb    = (const float*)d_in[2];
  const float* filt  = (const float*)d_in[3];
  const float* gate  = (const float*)d_in[4];
  const float* resw  = (const float*)d_in[5];
  const float* skipw = (const float*)d_in[6];
  const float* w1    = (const float*)d_in[7];
  const float* b1    = (const float*)d_in[8];
  const float* w2    = (const float*)d_in[9];
  const float* b2    = (const float*)d_in[10];
  float* out = (float*)d_out;

  // per-layer halo (valid-region chain), 64-aligned
  int P[NLAYER];
  P[NLAYER - 1] = 0;
  for (int i = NLAYER - 1; i >= 1; --i) {
    int d = 1 << (i % 10);
    P[i - 1] = ((P[i] + d + 63) / 64) * 64;
  }
  const int LO = ((P[0] + 1 + 63) / 64) * 64;  // = 4032

  // weight-split sizes (shorts)
  const size_t nFG = (size_t)NLAYER * 8192;
  const size_t nRes = (size_t)NLAYER * 4096;
  const size_t nSkip = (size_t)NLAYER * 16384;
  const size_t nE = 65536;
  const size_t wTot = 4 * nFG + 2 * nRes + 2 * nSkip + 4 * nE;

  auto need = [&](int tcv, int lov) -> size_t {
    return 2ull * NB * (size_t)(tcv + lov) * 256
         + (size_t)NLAYER * NB * (size_t)tcv * 64 * 2
         + wTot * 2;
  };
  int tc, lo, nchunk;
  if (ws_size >= need(TLEN, 0)) {
    tc = TLEN; lo = 0; nchunk = 1;
  } else if (ws_size >= need(TLEN / 2, LO)) {
    tc = TLEN / 2; lo = LO; nchunk = 2;
  } else {
    tc = TLEN / 4; lo = LO; nchunk = 4;
  }
  const int cext = tc + lo;

  const size_t NXTr = (size_t)NB * cext * 128;  // shorts
  unsigned short* xtA = (unsigned short*)d_ws;
  unsigned short* xtB = xtA + NXTr;
  unsigned short* outsB = xtB + NXTr;
  const size_t outsN = (size_t)NLAYER * NB * (size_t)tc * 64;
  unsigned short* wb = outsB + outsN;
  unsigned short* fH = wb;            unsigned short* fL = fH + nFG;
  unsigned short* gH = fL + nFG;      unsigned short* gL = gH + nFG;
  unsigned short* rH = gL + nFG;      unsigned short* rL = rH + nRes;
  unsigned short* sH = rL + nRes;     unsigned short* sL = sH + nSkip;
  unsigned short* e1H = sL + nSkip;   unsigned short* e1L = e1H + nE;
  unsigned short* e2H = e1L + nE;     unsigned short* e2L = e2H + nE;

  wn_prep_fg_k<<<dim3(NLAYER * 8192 / 256), dim3(256), 0, stream>>>(
      filt, gate, fH, fL, gH, gL);
  wn_repackA_k<<<dim3(NLAYER * 4096 / 256), dim3(256), 0, stream>>>(resw, rH, rL, 6, 12);
  wn_repackA_k<<<dim3(NLAYER * 16384 / 256), dim3(256), 0, stream>>>(skipw, sH, sL, 6, 14);
  wn_repackA_k<<<dim3(65536 / 256), dim3(256), 0, stream>>>(w1, e1H, e1L, 8, 16);
  wn_repackA_k<<<dim3(65536 / 256), dim3(256), 0, stream>>>(w2, e2H, e2L, 8, 16);

  for (int c = 0; c < nchunk; ++c) {
    int c0 = c * tc;
    int loc = (c == 0) ? 0 : lo;
    int ext = tc + loc;
    int base = c0 - loc;
    wn_causal_k<<<dim3(ext / 64, NB), dim3(256), 0, stream>>>(y, cw, cb, xtA, base, cext);
    unsigned short* xi = xtA;
    unsigned short* xo = xtB;
    for (int i = 0; i < NLAYER; ++i) {
      int d = 1 << (i % 10);
      int Pe = (c == 0) ? 0 : P[i];
      int nt = tc + Pe;
      wn_layer_k<<<dim3(nt / 64, NB), dim3(256), 0, stream>>>(
          xi, xo, outsB + (size_t)i * NB * (size_t)tc * 64,
          fH + (size_t)i * 8192, fL + (size_t)i * 8192,
          gH + (size_t)i * 8192, gL + (size_t)i * 8192,
          rH + (size_t)i * 4096, rL + (size_t)i * 4096,
          d, loc - Pe, loc, cext, tc);
      unsigned short* tmp = xi; xi = xo; xo = tmp;
    }
    wn_skipend_k<<<dim3(tc / 64, NB), dim3(256), 0, stream>>>(
        outsB, sH, sL, e1H, e1L, b1, e2H, e2L, b2, out, c0, tc);
  }
}

// Round 6
// 2044.658 us; speedup vs baseline: 1.0422x; 1.0422x over previous
//
#include <hip/hip_runtime.h>

#define TLEN 32768
#define NB 4
#define NLAYER 30

typedef short bf16x8 __attribute__((ext_vector_type(8)));
typedef float f32x16 __attribute__((ext_vector_type(16)));
#define MFMA32(a, b, c) __builtin_amdgcn_mfma_f32_32x32x16_bf16(a, b, c, 0, 0, 0)

__device__ __forceinline__ unsigned short bfh(float x) {
  unsigned int u = __float_as_uint(x);
  return (unsigned short)((u + 0x7fffu + ((u >> 16) & 1u)) >> 16);
}
__device__ __forceinline__ void fsplit(float x, unsigned short& h, unsigned short& l) {
  unsigned int u = __float_as_uint(x);
  unsigned int hb = (u + 0x7fffu + ((u >> 16) & 1u)) & 0xffff0000u;
  h = (unsigned short)(hb >> 16);
  l = bfh(x - __uint_as_float(hb));
}
__device__ __forceinline__ float bflo(unsigned int p) { return __uint_as_float(p << 16); }
__device__ __forceinline__ float bfhi2(unsigned int p) { return __uint_as_float(p & 0xffff0000u); }

__device__ __forceinline__ void split4(float4 v, uint2& h, uint2& l) {
  unsigned short h0, l0, h1, l1, h2, l2, h3, l3;
  fsplit(v.x, h0, l0); fsplit(v.y, h1, l1);
  fsplit(v.z, h2, l2); fsplit(v.w, h3, l3);
  h.x = (unsigned int)h0 | ((unsigned int)h1 << 16);
  h.y = (unsigned int)h2 | ((unsigned int)h3 << 16);
  l.x = (unsigned int)l0 | ((unsigned int)l1 << 16);
  l.y = (unsigned int)l2 | ((unsigned int)l3 << 16);
}
__device__ __forceinline__ bf16x8 asb(uint4 v) {
  union { uint4 u; bf16x8 b; } x; x.u = v; return x.b;
}
__device__ __forceinline__ bf16x8 asb2(uint2 a, uint2 b) {
  union { uint4 u; bf16x8 v; } x;
  x.u.x = a.x; x.u.y = a.y; x.u.z = b.x; x.u.w = b.y; return x.v;
}
__device__ __forceinline__ float fast_sigmoid(float x) { return 1.0f / (1.0f + __expf(-x)); }
__device__ __forceinline__ float fast_tanh(float x) { return 1.0f - 2.0f / (1.0f + __expf(2.0f * x)); }

// Fragment-ordered weight layout: uint4 index (((s>>5)*nkc + kc)*2 + q)*32 + (s&31)
// holds shorts (s, k=kc*16+q*8 .. +8).
__device__ __forceinline__ unsigned int fragOff(int s, int k, int nkc) {
  return ((((unsigned)(s >> 5) * nkc + (k >> 4)) * 2 + ((k >> 3) & 1)) * 32 + (s & 31)) * 8 + (k & 7);
}

// ---------------- prep ----------------

// chunk-local causal conv: x[b][ti][hi 0..63 | lo 64..127]
__global__ __launch_bounds__(256) void wn_causal_k(
    const float* __restrict__ y, const float* __restrict__ cw,
    const float* __restrict__ cb, unsigned short* __restrict__ xt, int base, int cext) {
  int ti = blockIdx.x * 64 + (threadIdx.x >> 2);
  int cg = (threadIdx.x & 3) << 4;
  int b = blockIdx.y;
  float yv = y[(size_t)b * TLEN + base + ti];
  unsigned short* o = xt + ((size_t)b * cext + ti) * 128 + cg;
  uint2 h[4], l[4];
#pragma unroll
  for (int j = 0; j < 4; ++j) {
    float4 w = *(const float4*)(cw + cg + 4 * j);
    float4 bb = *(const float4*)(cb + cg + 4 * j);
    float4 v; v.x = w.x * yv + bb.x; v.y = w.y * yv + bb.y;
    v.z = w.z * yv + bb.z; v.w = w.w * yv + bb.w;
    split4(v, h[j], l[j]);
  }
  uint4 H0, H1, L0, L1;
  H0.x = h[0].x; H0.y = h[0].y; H0.z = h[1].x; H0.w = h[1].y;
  H1.x = h[2].x; H1.y = h[2].y; H1.z = h[3].x; H1.w = h[3].y;
  L0.x = l[0].x; L0.y = l[0].y; L0.z = l[1].x; L0.w = l[1].y;
  L1.x = l[2].x; L1.y = l[2].y; L1.z = l[3].x; L1.w = l[3].y;
  *(uint4*)(o) = H0; *(uint4*)(o + 8) = H1;
  *(uint4*)(o + 64) = L0; *(uint4*)(o + 72) = L1;
}

// filt/gate -> fragment-ordered hi/lo (k = tap*64 + r)
__global__ __launch_bounds__(256) void wn_prep_fg_k(
    const float* __restrict__ filt, const float* __restrict__ gate,
    unsigned short* __restrict__ fH, unsigned short* __restrict__ fL,
    unsigned short* __restrict__ gH, unsigned short* __restrict__ gL) {
  int id = blockIdx.x * 256 + threadIdx.x;  // NLAYER*64*128
  int i = id >> 13; int rem = id & 8191; int d = rem >> 7; int k = rem & 127;
  int tap = k >> 6, r = k & 63;
  size_t sb = (size_t)i * 8192;
  unsigned int off = fragOff(d, k, 8);
  unsigned short h, l;
  fsplit(filt[sb + d * 128 + r * 2 + tap], h, l); fH[sb + off] = h; fL[sb + off] = l;
  fsplit(gate[sb + d * 128 + r * 2 + tap], h, l); gH[sb + off] = h; gL[sb + off] = l;
}

// generic row-major [layers][M][K] fp32 -> fragment-ordered hi/lo
__global__ __launch_bounds__(256) void wn_repackA_k(
    const float* __restrict__ src, unsigned short* __restrict__ dH,
    unsigned short* __restrict__ dL, int kShift, int mkShift) {
  int id = blockIdx.x * 256 + threadIdx.x;
  int layer = id >> mkShift;
  int rem = id & ((1 << mkShift) - 1);
  int s = rem >> kShift;
  int k = rem & ((1 << kShift) - 1);
  int nkc = 1 << (kShift - 4);
  unsigned int off = fragOff(s, k, nkc);
  size_t base = (size_t)layer << mkShift;
  unsigned short h, l;
  fsplit(src[base + rem], h, l);
  dH[base + off] = h; dL[base + off] = l;
}

// ---------------- layer kernel (chunk-local) ----------------
// outs is written in B-FRAGMENT order: per (b,tile): [fg=kc*2+q 0..8)[t 0..64)[8 shorts]
__global__ __launch_bounds__(256, 3) void wn_layer_k(
    const unsigned short* __restrict__ xin, unsigned short* __restrict__ xout,
    unsigned short* __restrict__ outp,  // [NB][ntiles][8][64][8] bf16
    const unsigned short* __restrict__ fH, const unsigned short* __restrict__ fL,
    const unsigned short* __restrict__ gH, const unsigned short* __restrict__ gL,
    const unsigned short* __restrict__ rH, const unsigned short* __restrict__ rL,
    int dil, int ti_start, int lo, int cext, int tc) {
  __shared__ unsigned short Xs[64 * 260];
  __shared__ unsigned short Os[64 * 132];  // [t][d hi 0..64 | d lo 64..128]

  const int tid = threadIdx.x;
  const int lane = tid & 63, wave = tid >> 6;
  const int q = lane >> 5, ln = lane & 31;
  const int b = blockIdx.y;
  const int ti0 = ti_start + (int)blockIdx.x * 64;
  const unsigned short* xb = xin + (size_t)b * cext * 128;

  // ---- stage X tile (coalesced copy) ----
  {
    int row = tid >> 2, cg = (tid & 3) << 4;
    const unsigned short* src = xb + (size_t)(ti0 + row) * 128 + cg;
    unsigned short* dh = &Xs[row * 260 + 64 + cg];
    unsigned short* dl = &Xs[row * 260 + 192 + cg];
    {
      uint4 h0 = *(const uint4*)(src);
      uint4 h1 = *(const uint4*)(src + 8);
      uint4 l0 = *(const uint4*)(src + 64);
      uint4 l1 = *(const uint4*)(src + 72);
      uint2 t;
      t.x = h0.x; t.y = h0.y; *(uint2*)(dh + 0) = t;
      t.x = h0.z; t.y = h0.w; *(uint2*)(dh + 4) = t;
      t.x = h1.x; t.y = h1.y; *(uint2*)(dh + 8) = t;
      t.x = h1.z; t.y = h1.w; *(uint2*)(dh + 12) = t;
      t.x = l0.x; t.y = l0.y; *(uint2*)(dl + 0) = t;
      t.x = l0.z; t.y = l0.w; *(uint2*)(dl + 4) = t;
      t.x = l1.x; t.y = l1.y; *(uint2*)(dl + 8) = t;
      t.x = l1.z; t.y = l1.w; *(uint2*)(dl + 12) = t;
    }
    int ts = ti0 + row - dil;
    dh = &Xs[row * 260 + cg];
    dl = &Xs[row * 260 + 128 + cg];
    if (ts >= 0) {
      const unsigned short* s2 = xb + (size_t)ts * 128 + cg;
      uint4 h0 = *(const uint4*)(s2);
      uint4 h1 = *(const uint4*)(s2 + 8);
      uint4 l0 = *(const uint4*)(s2 + 64);
      uint4 l1 = *(const uint4*)(s2 + 72);
      uint2 t;
      t.x = h0.x; t.y = h0.y; *(uint2*)(dh + 0) = t;
      t.x = h0.z; t.y = h0.w; *(uint2*)(dh + 4) = t;
      t.x = h1.x; t.y = h1.y; *(uint2*)(dh + 8) = t;
      t.x = h1.z; t.y = h1.w; *(uint2*)(dh + 12) = t;
      t.x = l0.x; t.y = l0.y; *(uint2*)(dl + 0) = t;
      t.x = l0.z; t.y = l0.w; *(uint2*)(dl + 4) = t;
      t.x = l1.x; t.y = l1.y; *(uint2*)(dl + 8) = t;
      t.x = l1.z; t.y = l1.w; *(uint2*)(dl + 12) = t;
    } else {
      uint2 z; z.x = 0; z.y = 0;
#pragma unroll
      for (int j = 0; j < 4; ++j) { *(uint2*)(dh + 4 * j) = z; *(uint2*)(dl + 4 * j) = z; }
    }
  }

  const int dblk = wave >> 1, tblk = wave & 1;

  // conv A-frags (fragment-ordered, coalesced): hi register-resident, lo streamed
  uint4 afh[8], agh[8];
  const uint4* pfh = (const uint4*)fH;
  const uint4* pfl = (const uint4*)fL;
  const uint4* pgh = (const uint4*)gH;
  const uint4* pgl = (const uint4*)gL;
  const int abase = dblk * 512 + q * 32 + ln;
#pragma unroll
  for (int kc = 0; kc < 8; ++kc) {
    afh[kc] = pfh[abase + kc * 64];
    agh[kc] = pgh[abase + kc * 64];
  }
  __syncthreads();

  f32x16 accF, accG;
#pragma unroll
  for (int i = 0; i < 16; ++i) { accF[i] = 0.f; accG[i] = 0.f; }

  const unsigned short* xrow = &Xs[(tblk * 32 + ln) * 260];
#pragma unroll
  for (int kc = 0; kc < 8; ++kc) {
    uint4 fl = pfl[abase + kc * 64];
    uint4 gl = pgl[abase + kc * 64];
    uint2 h0 = *(const uint2*)(xrow + kc * 16 + q * 8);
    uint2 h1 = *(const uint2*)(xrow + kc * 16 + q * 8 + 4);
    uint2 l0 = *(const uint2*)(xrow + 128 + kc * 16 + q * 8);
    uint2 l1 = *(const uint2*)(xrow + 128 + kc * 16 + q * 8 + 4);
    bf16x8 bh = asb2(h0, h1), bl = asb2(l0, l1);
    accF = MFMA32(asb(afh[kc]), bh, accF);
    accF = MFMA32(asb(afh[kc]), bl, accF);
    accF = MFMA32(asb(fl), bh, accF);
    accG = MFMA32(asb(agh[kc]), bh, accG);
    accG = MFMA32(asb(agh[kc]), bl, accG);
    accG = MFMA32(asb(gl), bh, accG);
  }

  // ---- activation -> Os (hi/lo) ----
  {
    int trow = tblk * 32 + ln;
    unsigned short* orow = &Os[trow * 132 + dblk * 32];
#pragma unroll
    for (int g = 0; g < 4; ++g) {
      int dofs = 8 * g + 4 * q;
      unsigned short oh[4], ol[4];
#pragma unroll
      for (int j = 0; j < 4; ++j) {
        float f = fast_tanh(accF[g * 4 + j]) * fast_sigmoid(accG[g * 4 + j]);
        fsplit(f, oh[j], ol[j]);
      }
      uint2 hv, lv;
      hv.x = (unsigned int)oh[0] | ((unsigned int)oh[1] << 16);
      hv.y = (unsigned int)oh[2] | ((unsigned int)oh[3] << 16);
      lv.x = (unsigned int)ol[0] | ((unsigned int)ol[1] << 16);
      lv.y = (unsigned int)ol[2] | ((unsigned int)ol[3] << 16);
      *(uint2*)(orow + dofs) = hv;
      *(uint2*)(orow + 64 + dofs) = lv;
    }
  }
  __syncthreads();

  // ---- outs store in B-fragment order (hi halves from Os), coalesced ----
  if (ti0 >= lo) {
    int tile = (ti0 - lo) >> 6;
    int t = tid & 63, fg = tid >> 6;  // fg 0..3 here, fg+4 below
    const unsigned short* sp = &Os[t * 132];
    uint2 a0 = *(const uint2*)(sp + fg * 8);
    uint2 a1 = *(const uint2*)(sp + fg * 8 + 4);
    uint2 c0 = *(const uint2*)(sp + 32 + fg * 8);
    uint2 c1 = *(const uint2*)(sp + 32 + fg * 8 + 4);
    uint4 v0, v1;
    v0.x = a0.x; v0.y = a0.y; v0.z = a1.x; v0.w = a1.y;
    v1.x = c0.x; v1.y = c0.y; v1.z = c1.x; v1.w = c1.y;
    unsigned short* dpb = outp + ((size_t)b * (tc >> 6) + tile) * 4096;
    *(uint4*)(dpb + fg * 512 + t * 8) = v0;
    *(uint4*)(dpb + (fg + 4) * 512 + t * 8) = v1;
  }

  // ---- residual: xout = x + res_w @ out (store via LDS repack) ----
  {
    const int rblk = wave >> 1, tb2 = wave & 1;
    const int rb4 = rblk * 256 + q * 32 + ln;
    const uint4* prh = (const uint4*)rH;
    const uint4* prl = (const uint4*)rL;
    uint4 arh[4], arl[4];
#pragma unroll
    for (int kc = 0; kc < 4; ++kc) {
      arh[kc] = prh[rb4 + kc * 64];
      arl[kc] = prl[rb4 + kc * 64];
    }
    f32x16 accR;
#pragma unroll
    for (int i = 0; i < 16; ++i) accR[i] = 0.f;
    const int t = tb2 * 32 + ln;
    const unsigned short* orow = &Os[t * 132];
#pragma unroll
    for (int kc = 0; kc < 4; ++kc) {
      uint2 h0 = *(const uint2*)(orow + kc * 16 + q * 8);
      uint2 h1 = *(const uint2*)(orow + kc * 16 + q * 8 + 4);
      uint2 l0 = *(const uint2*)(orow + 64 + kc * 16 + q * 8);
      uint2 l1 = *(const uint2*)(orow + 64 + kc * 16 + q * 8 + 4);
      bf16x8 bh = asb2(h0, h1), bl = asb2(l0, l1);
      accR = MFMA32(asb(arh[kc]), bh, accR);
      accR = MFMA32(asb(arh[kc]), bl, accR);
      accR = MFMA32(asb(arl[kc]), bh, accR);
    }
    __syncthreads();  // all Os reads (outs copy + accR MFMAs) complete
    // v = accR + x -> split -> Os as [t][hi 0..64 | lo 64..128]
#pragma unroll
    for (int g = 0; g < 4; ++g) {
      int rbase = rblk * 32 + 8 * g + 4 * q;
      uint2 xh = *(const uint2*)&Xs[t * 260 + 64 + rbase];
      uint2 xl = *(const uint2*)&Xs[t * 260 + 192 + rbase];
      float4 v;
      v.x = accR[g * 4 + 0] + bflo(xh.x) + bflo(xl.x);
      v.y = accR[g * 4 + 1] + bfhi2(xh.x) + bfhi2(xl.x);
      v.z = accR[g * 4 + 2] + bflo(xh.y) + bflo(xl.y);
      v.w = accR[g * 4 + 3] + bfhi2(xh.y) + bfhi2(xl.y);
      uint2 hv, lv;
      split4(v, hv, lv);
      *(uint2*)&Os[t * 132 + rbase] = hv;
      *(uint2*)&Os[t * 132 + 64 + rbase] = lv;
    }
    __syncthreads();
    // coalesced xout copy: 4 threads/row, 64B each
    int row = tid >> 2, seg = (tid & 3) << 5;
    const unsigned short* sp = &Os[row * 132 + seg];
    uint2 a0 = *(const uint2*)(sp);
    uint2 a1 = *(const uint2*)(sp + 4);
    uint2 a2 = *(const uint2*)(sp + 8);
    uint2 a3 = *(const uint2*)(sp + 12);
    uint2 a4 = *(const uint2*)(sp + 16);
    uint2 a5 = *(const uint2*)(sp + 20);
    uint2 a6 = *(const uint2*)(sp + 24);
    uint2 a7 = *(const uint2*)(sp + 28);
    uint4 w0, w1, w2, w3;
    w0.x = a0.x; w0.y = a0.y; w0.z = a1.x; w0.w = a1.y;
    w1.x = a2.x; w1.y = a2.y; w1.z = a3.x; w1.w = a3.y;
    w2.x = a4.x; w2.y = a4.y; w2.z = a5.x; w2.w = a5.y;
    w3.x = a6.x; w3.y = a6.y; w3.z = a7.x; w3.w = a7.y;
    unsigned short* dp = xout + ((size_t)b * cext + ti0 + row) * 128 + seg;
    *(uint4*)(dp) = w0; *(uint4*)(dp + 8) = w1;
    *(uint4*)(dp + 16) = w2; *(uint4*)(dp + 24) = w3;
  }
}

// ---------------- fused skip-sum + head (per chunk) ----------------
// Skip loop: barrier-free, LDS-free, software-pipelined with sched_barrier(0)
// fences. Issue order per layer i: [A-hi/A-lo for i (L2)] [B for i+1 (HBM)]
// | fence | [32 MFMAs for i] | fence |. First MFMA waits vmcnt down to A only;
// the next layer's 8 HBM loads stay in flight across the whole compute phase.
__global__ __launch_bounds__(256, 2) void wn_skipend_k(
    const unsigned short* __restrict__ outs,  // [30][NB][ntiles][8][64][8]
    const unsigned short* __restrict__ sH, const unsigned short* __restrict__ sL,
    const unsigned short* __restrict__ e1H, const unsigned short* __restrict__ e1L,
    const float* __restrict__ b1,
    const unsigned short* __restrict__ e2H, const unsigned short* __restrict__ e2L,
    const float* __restrict__ b2, float* __restrict__ out, int c0, int tc) {
  __shared__ unsigned short SM[64 * 260];  // Hs for head phases; fp32 out repack

  const int tid = threadIdx.x;
  const int lane = tid & 63, wave = tid >> 6;
  const int q = lane >> 5, ln = lane & 31;
  const int b = blockIdx.y;
  const int tl0 = (int)blockIdx.x * 64;

  f32x16 acc[4];  // [sblk][tt]
#pragma unroll
  for (int a = 0; a < 4; ++a)
#pragma unroll
    for (int i = 0; i < 16; ++i) acc[a][i] = 0.f;

  const int ntiles = tc >> 6;
  const size_t lstride4 = (size_t)NB * tc * 8;  // uint4 per layer
  const uint4* pbl = (const uint4*)outs + ((size_t)b * ntiles + blockIdx.x) * 512
                   + q * 64 + ln;               // lane-resolved fragment base
  const int ab = wave * 512 + q * 32 + ln;      // fragment-ordered A base (uint4)
  const uint4* pa4 = (const uint4*)sH;
  const uint4* pl4 = (const uint4*)sL;

  uint4 bbA[8], bbB[8], ah[8], al[8];

#define BLD(i, bb)                                               \
  {                                                              \
    const uint4* pb_ = pbl + (size_t)(i) * lstride4;             \
    _Pragma("unroll")                                            \
    for (int kc = 0; kc < 4; ++kc) {                             \
      bb[kc * 2] = pb_[kc * 128];                                \
      bb[kc * 2 + 1] = pb_[kc * 128 + 32];                       \
    }                                                            \
  }

#define ALD(i)                                                   \
  {                                                              \
    const uint4* pa_ = pa4 + (size_t)(i) * 2048;                 \
    const uint4* pl_ = pl4 + (size_t)(i) * 2048;                 \
    _Pragma("unroll")                                            \
    for (int kc = 0; kc < 4; ++kc) {                             \
      ah[kc * 2] = pa_[ab + kc * 64];                            \
      ah[kc * 2 + 1] = pa_[ab + 256 + kc * 64];                  \
      al[kc * 2] = pl_[ab + kc * 64];                            \
      al[kc * 2 + 1] = pl_[ab + 256 + kc * 64];                  \
    }                                                            \
  }

#define CP(bb)                                                                \
  {                                                                           \
    _Pragma("unroll")                                                         \
    for (int kc = 0; kc < 4; ++kc) {                                          \
      _Pragma("unroll")                                                       \
      for (int sblk = 0; sblk < 2; ++sblk) {                                  \
        acc[sblk * 2 + 0] = MFMA32(asb(ah[kc * 2 + sblk]), asb(bb[kc * 2]),   \
                                   acc[sblk * 2 + 0]);                        \
        acc[sblk * 2 + 0] = MFMA32(asb(al[kc * 2 + sblk]), asb(bb[kc * 2]),   \
                                   acc[sblk * 2 + 0]);                        \
        acc[sblk * 2 + 1] = MFMA32(asb(ah[kc * 2 + sblk]), asb(bb[kc * 2 + 1]),\
                                   acc[sblk * 2 + 1]);                        \
        acc[sblk * 2 + 1] = MFMA32(asb(al[kc * 2 + sblk]), asb(bb[kc * 2 + 1]),\
                                   acc[sblk * 2 + 1]);                        \
      }                                                                       \
    }                                                                         \
  }

  BLD(0, bbA);
  for (int i = 0; i < NLAYER; i += 2) {
    // even layer i: consume bbA, prefetch bbB
    ALD(i);
    BLD(i + 1, bbB);
    __builtin_amdgcn_sched_barrier(0);
    CP(bbA);
    __builtin_amdgcn_sched_barrier(0);
    // odd layer i+1: consume bbB, prefetch bbA
    ALD(i + 1);
    if (i + 2 < NLAYER) BLD(i + 2, bbA);
    __builtin_amdgcn_sched_barrier(0);
    CP(bbB);
    __builtin_amdgcn_sched_barrier(0);
  }
#undef BLD
#undef ALD
#undef CP

  // h = relu(skip) -> Hs bf16 (row stride 260); first LDS touch
#pragma unroll
  for (int sblk = 0; sblk < 2; ++sblk)
#pragma unroll
    for (int tt = 0; tt < 2; ++tt) {
      int t = tt * 32 + ln;
#pragma unroll
      for (int g = 0; g < 4; ++g) {
        int s = wave * 64 + sblk * 32 + 8 * g + 4 * q;
        unsigned short h0 = bfh(fmaxf(acc[sblk * 2 + tt][g * 4 + 0], 0.f));
        unsigned short h1 = bfh(fmaxf(acc[sblk * 2 + tt][g * 4 + 1], 0.f));
        unsigned short h2 = bfh(fmaxf(acc[sblk * 2 + tt][g * 4 + 2], 0.f));
        unsigned short h3 = bfh(fmaxf(acc[sblk * 2 + tt][g * 4 + 3], 0.f));
        uint2 hv;
        hv.x = (unsigned int)h0 | ((unsigned int)h1 << 16);
        hv.y = (unsigned int)h2 | ((unsigned int)h3 << 16);
        *(uint2*)&SM[t * 260 + s] = hv;
      }
    }
  __syncthreads();

  // e1: acc = e1 @ h
#pragma unroll
  for (int a = 0; a < 4; ++a)
#pragma unroll
    for (int i = 0; i < 16; ++i) acc[a][i] = 0.f;
  const uint4* p1h = (const uint4*)e1H;
  const uint4* p1l = (const uint4*)e1L;
  const int eb = wave * 2048 + q * 32 + ln;
#pragma unroll 4
  for (int kc = 0; kc < 16; ++kc) {
#pragma unroll
    for (int ot = 0; ot < 2; ++ot) {
      uint4 ah2 = p1h[eb + ot * 1024 + kc * 64];
      uint4 al2 = p1l[eb + ot * 1024 + kc * 64];
#pragma unroll
      for (int tt = 0; tt < 2; ++tt) {
        uint2 b0 = *(const uint2*)&SM[(tt * 32 + ln) * 260 + kc * 16 + q * 8];
        uint2 b1v = *(const uint2*)&SM[(tt * 32 + ln) * 260 + kc * 16 + q * 8 + 4];
        bf16x8 bb = asb2(b0, b1v);
        acc[ot * 2 + tt] = MFMA32(asb(ah2), bb, acc[ot * 2 + tt]);
        acc[ot * 2 + tt] = MFMA32(asb(al2), bb, acc[ot * 2 + tt]);
      }
    }
  }
  __syncthreads();
  // h2 = relu(acc + b1) -> Hs
#pragma unroll
  for (int ot = 0; ot < 2; ++ot)
#pragma unroll
    for (int tt = 0; tt < 2; ++tt) {
      int t = tt * 32 + ln;
#pragma unroll
      for (int g = 0; g < 4; ++g) {
        int o = wave * 64 + ot * 32 + 8 * g + 4 * q;
        float4 bb = *(const float4*)(b1 + o);
        unsigned short h0 = bfh(fmaxf(acc[ot * 2 + tt][g * 4 + 0] + bb.x, 0.f));
        unsigned short h1 = bfh(fmaxf(acc[ot * 2 + tt][g * 4 + 1] + bb.y, 0.f));
        unsigned short h2 = bfh(fmaxf(acc[ot * 2 + tt][g * 4 + 2] + bb.z, 0.f));
        unsigned short h3 = bfh(fmaxf(acc[ot * 2 + tt][g * 4 + 3] + bb.w, 0.f));
        uint2 hv;
        hv.x = (unsigned int)h0 | ((unsigned int)h1 << 16);
        hv.y = (unsigned int)h2 | ((unsigned int)h3 << 16);
        *(uint2*)&SM[t * 260 + o] = hv;
      }
    }
  __syncthreads();

  // e2: acc = e2 @ h2
#pragma unroll
  for (int a = 0; a < 4; ++a)
#pragma unroll
    for (int i = 0; i < 16; ++i) acc[a][i] = 0.f;
  const uint4* p2h = (const uint4*)e2H;
  const uint4* p2l = (const uint4*)e2L;
#pragma unroll 4
  for (int kc = 0; kc < 16; ++kc) {
#pragma unroll
    for (int ot = 0; ot < 2; ++ot) {
      uint4 ah2 = p2h[eb + ot * 1024 + kc * 64];
      uint4 al2 = p2l[eb + ot * 1024 + kc * 64];
#pragma unroll
      for (int tt = 0; tt < 2; ++tt) {
        uint2 b0 = *(const uint2*)&SM[(tt * 32 + ln) * 260 + kc * 16 + q * 8];
        uint2 b1v = *(const uint2*)&SM[(tt * 32 + ln) * 260 + kc * 16 + q * 8 + 4];
        bf16x8 bb = asb2(b0, b1v);
        acc[ot * 2 + tt] = MFMA32(asb(ah2), bb, acc[ot * 2 + tt]);
        acc[ot * 2 + tt] = MFMA32(asb(al2), bb, acc[ot * 2 + tt]);
      }
    }
  }
  __syncthreads();  // h2 reads done; SM reusable as fp32 repack buffer

  // final store via LDS repack (two 32-row half-passes), full-sector coalesced
  float* SMf = (float*)SM;  // [32][260] fp32
#pragma unroll
  for (int hp = 0; hp < 2; ++hp) {
#pragma unroll
    for (int ot = 0; ot < 2; ++ot)
#pragma unroll
      for (int g = 0; g < 4; ++g) {
        int o = wave * 64 + ot * 32 + 8 * g + 4 * q;
        float4 bb = *(const float4*)(b2 + o);
        float2 v0, v1;
        v0.x = acc[ot * 2 + hp][g * 4 + 0] + bb.x;
        v0.y = acc[ot * 2 + hp][g * 4 + 1] + bb.y;
        v1.x = acc[ot * 2 + hp][g * 4 + 2] + bb.z;
        v1.y = acc[ot * 2 + hp][g * 4 + 3] + bb.w;
        *(float2*)&SMf[ln * 260 + o] = v0;
        *(float2*)&SMf[ln * 260 + o + 2] = v1;
      }
    __syncthreads();
    {
      // 8 threads/row, each 16B at 16B-consecutive addresses -> full 128B rows
      int row = tid >> 3, c4 = (tid & 7) << 2;
      float* op = out + ((size_t)b * TLEN + c0 + tl0 + hp * 32 + row) * 256 + c4;
      const float* spf = &SMf[row * 260 + c4];
#pragma unroll
      for (int j = 0; j < 8; ++j) *(float4*)(op + 32 * j) = *(const float4*)(spf + 32 * j);
    }
    if (hp == 0) __syncthreads();
  }
}

extern "C" void kernel_launch(void* const* d_in, const int* in_sizes, int n_in,
                              void* d_out, int out_size, void* d_ws,
                              size_t ws_size, hipStream_t stream) {
  (void)in_sizes; (void)n_in; (void)out_size;
  const float* y     = (const float*)d_in[0];
  const float* cw    = (const float*)d_in[1];
  const float* cb    = (const float*)d_in[2];
  const float* filt  = (const float*)d_in[3];
  const float* gate  = (const float*)d_in[4];
  const float* resw  = (const float*)d_in[5];
  const float* skipw = (const float*)d_in[6];
  const float* w1    = (const float*)d_in[7];
  const float* b1    = (const float*)d_in[8];
  const float* w2    = (const float*)d_in[9];
  const float* b2    = (const float*)d_in[10];
  float* out = (float*)d_out;

  // per-layer halo (valid-region chain), 64-aligned
  int P[NLAYER];
  P[NLAYER - 1] = 0;
  for (int i = NLAYER - 1; i >= 1; --i) {
    int d = 1 << (i % 10);
    P[i - 1] = ((P[i] + d + 63) / 64) * 64;
  }
  const int LO = ((P[0] + 1 + 63) / 64) * 64;  // = 4032

  // weight-split sizes (shorts)
  const size_t nFG = (size_t)NLAYER * 8192;
  const size_t nRes = (size_t)NLAYER * 4096;
  const size_t nSkip = (size_t)NLAYER * 16384;
  const size_t nE = 65536;
  const size_t wTot = 4 * nFG + 2 * nRes + 2 * nSkip + 4 * nE;

  auto need = [&](int tcv, int lov) -> size_t {
    return 2ull * NB * (size_t)(tcv + lov) * 256
         + (size_t)NLAYER * NB * (size_t)tcv * 64 * 2
         + wTot * 2;
  };
  int tc, lo, nchunk;
  if (ws_size >= need(TLEN, 0)) {
    tc = TLEN; lo = 0; nchunk = 1;
  } else if (ws_size >= need(TLEN / 2, LO)) {
    tc = TLEN / 2; lo = LO; nchunk = 2;
  } else {
    tc = TLEN / 4; lo = LO; nchunk = 4;
  }
  const int cext = tc + lo;

  const size_t NXTr = (size_t)NB * cext * 128;  // shorts
  unsigned short* xtA = (unsigned short*)d_ws;
  unsigned short* xtB = xtA + NXTr;
  unsigned short* outsB = xtB + NXTr;
  const size_t outsN = (size_t)NLAYER * NB * (size_t)tc * 64;
  unsigned short* wb = outsB + outsN;
  unsigned short* fH = wb;            unsigned short* fL = fH + nFG;
  unsigned short* gH = fL + nFG;      unsigned short* gL = gH + nFG;
  unsigned short* rH = gL + nFG;      unsigned short* rL = rH + nRes;
  unsigned short* sH = rL + nRes;     unsigned short* sL = sH + nSkip;
  unsigned short* e1H = sL + nSkip;   unsigned short* e1L = e1H + nE;
  unsigned short* e2H = e1L + nE;     unsigned short* e2L = e2H + nE;

  wn_prep_fg_k<<<dim3(NLAYER * 8192 / 256), dim3(256), 0, stream>>>(
      filt, gate, fH, fL, gH, gL);
  wn_repackA_k<<<dim3(NLAYER * 4096 / 256), dim3(256), 0, stream>>>(resw, rH, rL, 6, 12);
  wn_repackA_k<<<dim3(NLAYER * 16384 / 256), dim3(256), 0, stream>>>(skipw, sH, sL, 6, 14);
  wn_repackA_k<<<dim3(65536 / 256), dim3(256), 0, stream>>>(w1, e1H, e1L, 8, 16);
  wn_repackA_k<<<dim3(65536 / 256), dim3(256), 0, stream>>>(w2, e2H, e2L, 8, 16);

  for (int c = 0; c < nchunk; ++c) {
    int c0 = c * tc;
    int loc = (c == 0) ? 0 : lo;
    int ext = tc + loc;
    int base = c0 - loc;
    wn_causal_k<<<dim3(ext / 64, NB), dim3(256), 0, stream>>>(y, cw, cb, xtA, base, cext);
    unsigned short* xi = xtA;
    unsigned short* xo = xtB;
    for (int i = 0; i < NLAYER; ++i) {
      int d = 1 << (i % 10);
      int Pe = (c == 0) ? 0 : P[i];
      int nt = tc + Pe;
      wn_layer_k<<<dim3(nt / 64, NB), dim3(256), 0, stream>>>(
          xi, xo, outsB + (size_t)i * NB * (size_t)tc * 64,
          fH + (size_t)i * 8192, fL + (size_t)i * 8192,
          gH + (size_t)i * 8192, gL + (size_t)i * 8192,
          rH + (size_t)i * 4096, rL + (size_t)i * 4096,
          d, loc - Pe, loc, cext, tc);
      unsigned short* tmp = xi; xi = xo; xo = tmp;
    }
    wn_skipend_k<<<dim3(tc / 64, NB), dim3(256), 0, stream>>>(
        outsB, sH, sL, e1H, e1L, b1, e2H, e2L, b2, out, c0, tc);
  }
}